// Round 3
// baseline (370.606 us; speedup 1.0000x reference)
//
#include <hip/hip_runtime.h>

// Problem constants (from reference setup_inputs)
#define BATCHES 64
#define PATCHES 4096
#define PATCH_ELEMS 256          // 16*16
#define NBINS 257                // patch_size^2 + 1
#define BLOCKS_PER_BATCH 32
#define PATCHES_PER_BLOCK (PATCHES / BLOCKS_PER_BATCH)  // 128

// v3: contiguous wave-loads + DPP reduce + ILP-8.
//  - One patch = 1 KiB = one fully-contiguous wave load (lane i -> float4 at
//    patch_base + 16*i): 16 cache-line requests per instr, the minimum.
//  - 8 patches (8 loads, 8 KiB) in flight per wave-iteration, 8 independent
//    reduction chains interleaved -> latency hidden.
//  - Cross-lane reduce via DPP v_add chains (row_shr 1/2/4/8, row_bcast 15/31):
//    pure VALU, no LDS-pipe (ds_bpermute) traffic, total lands in lane 63.
//  - #pragma unroll 1 on outer loop pins VGPR use (~60) for 32 waves/CU.

template <int CTRL>
__device__ __forceinline__ float dpp_add(float v) {
    // masked/out-of-bounds lanes contribute 0 (old=0, bound_ctrl=true)
    int t = __builtin_amdgcn_update_dpp(0, __float_as_int(v), CTRL, 0xF, 0xF, true);
    return v + __int_as_float(t);
}

__global__ __launch_bounds__(256)
void Probability_66048007078103_kernel(const float* __restrict__ in,
                                       float* __restrict__ out) {
    __shared__ int hist[NBINS];
    for (int i = threadIdx.x; i < NBINS; i += 256) hist[i] = 0;
    __syncthreads();

    const int batch = blockIdx.x & (BATCHES - 1);   // consecutive blocks -> different batches (XCD spread)
    const int slice = blockIdx.x >> 6;              // 0..31
    const int lane  = threadIdx.x & 63;
    const int wave  = threadIdx.x >> 6;             // 0..3

    const float4* in4 = (const float4*)(in + (size_t)batch * PATCHES * PATCH_ELEMS);
    const int p0 = slice * PATCHES_PER_BLOCK + wave * 32;   // 32 patches per wave

    #pragma unroll 1
    for (int i = 0; i < 4; ++i) {
        const int p = p0 + i * 8;
        float4 v0 = in4[(size_t)(p + 0) * 64 + lane];
        float4 v1 = in4[(size_t)(p + 1) * 64 + lane];
        float4 v2 = in4[(size_t)(p + 2) * 64 + lane];
        float4 v3 = in4[(size_t)(p + 3) * 64 + lane];
        float4 v4 = in4[(size_t)(p + 4) * 64 + lane];
        float4 v5 = in4[(size_t)(p + 5) * 64 + lane];
        float4 v6 = in4[(size_t)(p + 6) * 64 + lane];
        float4 v7 = in4[(size_t)(p + 7) * 64 + lane];

        float s[8];
        s[0] = (v0.x + v0.y) + (v0.z + v0.w);
        s[1] = (v1.x + v1.y) + (v1.z + v1.w);
        s[2] = (v2.x + v2.y) + (v2.z + v2.w);
        s[3] = (v3.x + v3.y) + (v3.z + v3.w);
        s[4] = (v4.x + v4.y) + (v4.z + v4.w);
        s[5] = (v5.x + v5.y) + (v5.z + v5.w);
        s[6] = (v6.x + v6.y) + (v6.z + v6.w);
        s[7] = (v7.x + v7.y) + (v7.z + v7.w);

        // 6-level DPP tree, 8 chains interleaved (level-major for ILP).
        #pragma unroll
        for (int j = 0; j < 8; ++j) s[j] = dpp_add<0x111>(s[j]);  // row_shr:1
        #pragma unroll
        for (int j = 0; j < 8; ++j) s[j] = dpp_add<0x112>(s[j]);  // row_shr:2
        #pragma unroll
        for (int j = 0; j < 8; ++j) s[j] = dpp_add<0x114>(s[j]);  // row_shr:4
        #pragma unroll
        for (int j = 0; j < 8; ++j) s[j] = dpp_add<0x118>(s[j]);  // row_shr:8
        #pragma unroll
        for (int j = 0; j < 8; ++j) s[j] = dpp_add<0x142>(s[j]);  // row_bcast:15
        #pragma unroll
        for (int j = 0; j < 8; ++j) s[j] = dpp_add<0x143>(s[j]);  // row_bcast:31

        if (lane == 63) {
            #pragma unroll
            for (int j = 0; j < 8; ++j)
                atomicAdd(&hist[(int)(s[j] + 0.5f)], 1);
        }
    }
    __syncthreads();

    const float invP = 1.0f / (float)PATCHES;
    for (int i = threadIdx.x; i < NBINS; i += 256) {
        int c = hist[i];
        if (c) atomicAdd(&out[batch * NBINS + i], (float)c * invP);
    }
}

extern "C" void kernel_launch(void* const* d_in, const int* in_sizes, int n_in,
                              void* d_out, int out_size, void* d_ws, size_t ws_size,
                              hipStream_t stream) {
    const float* in = (const float*)d_in[0];
    float* out = (float*)d_out;
    // d_out is poisoned to 0xAA before every timed launch — zero it (memset node is graph-capturable).
    hipMemsetAsync(out, 0, (size_t)out_size * sizeof(float), stream);
    Probability_66048007078103_kernel<<<BATCHES * BLOCKS_PER_BATCH, 256, 0, stream>>>(in, out);
}

// Round 4
// 353.016 us; speedup vs baseline: 1.0498x; 1.0498x over previous
//
#include <hip/hip_runtime.h>

// Problem constants (from reference setup_inputs)
#define BATCHES 64
#define PATCHES 4096
#define PATCH_ELEMS 256          // 16*16
#define NBINS 257                // patch_size^2 + 1
#define BLOCKS_PER_BATCH 32
#define PATCHES_PER_BLOCK (PATCHES / BLOCKS_PER_BATCH)  // 128

// v4 == v2 (best measured: 352.7 µs total). 16 lanes per patch. Each lane
// sums 16 contiguous elements (4x float4, all loads independent, issued
// up-front), then a 4-level width-16 shuffle reduce yields 4 patch sums per
// wave-group; 8 patches per iteration -> 8 dwordx4 loads in flight per lane.
// Session evidence (R1-R3): three structurally disjoint variants (6 ds-ops vs
// 1 vs 0 per patch; 1024 vs 2048 blocks) all land 352-370 µs total -> kernel
// portion is ~45-60 µs ~= the 42 µs mandatory-read roofline (256 MiB once);
// the rest is harness-fixed traffic (1 GiB ws-poison fill @84% peak = 160 µs,
// 256 MiB d_in restore ~80 µs, reset dispatches/gaps).
__global__ __launch_bounds__(256)
void Probability_66048007078103_kernel(const float* __restrict__ in,
                                       float* __restrict__ out) {
    __shared__ int hist[NBINS];
    for (int i = threadIdx.x; i < NBINS; i += 256) hist[i] = 0;
    __syncthreads();

    const int batch = blockIdx.x & (BATCHES - 1);   // consecutive blocks -> different batches (XCD spread)
    const int slice = blockIdx.x >> 6;              // 0..31
    const int lane  = threadIdx.x & 63;
    const int wave  = threadIdx.x >> 6;             // 0..3
    const int sub   = lane >> 4;                    // patch-within-group 0..3
    const int t     = lane & 15;                    // 16 lanes per patch

    const float4* in4 = (const float4*)(in + (size_t)batch * PATCHES * PATCH_ELEMS);
    const int p_start = slice * PATCHES_PER_BLOCK;  // 128 patches per block

    // Each wave handles 32 patches: 4 iterations x 8 patches (2 groups of 4).
    for (int i = 0; i < 4; ++i) {
        const int pA = p_start + i * 32 + wave * 8 + sub;       // group A patch
        const int pB = pA + 4;                                  // group B patch
        const float4* a = &in4[(size_t)pA * 64 + t * 4];
        const float4* b = &in4[(size_t)pB * 64 + t * 4];
        // 8 independent 16B loads in flight
        float4 a0 = a[0], a1 = a[1], a2 = a[2], a3 = a[3];
        float4 b0 = b[0], b1 = b[1], b2 = b[2], b3 = b[3];
        float sA = ((a0.x + a0.y) + (a0.z + a0.w)) + ((a1.x + a1.y) + (a1.z + a1.w))
                 + ((a2.x + a2.y) + (a2.z + a2.w)) + ((a3.x + a3.y) + (a3.z + a3.w));
        float sB = ((b0.x + b0.y) + (b0.z + b0.w)) + ((b1.x + b1.y) + (b1.z + b1.w))
                 + ((b2.x + b2.y) + (b2.z + b2.w)) + ((b3.x + b3.y) + (b3.z + b3.w));
        // reduce across the 16 lanes of each patch (two chains interleave)
        #pragma unroll
        for (int off = 8; off > 0; off >>= 1) {
            sA += __shfl_down(sA, off, 16);
            sB += __shfl_down(sB, off, 16);
        }
        if (t == 0) {
            atomicAdd(&hist[(int)(sA + 0.5f)], 1);
            atomicAdd(&hist[(int)(sB + 0.5f)], 1);
        }
    }
    __syncthreads();

    const float invP = 1.0f / (float)PATCHES;
    for (int i = threadIdx.x; i < NBINS; i += 256) {
        int c = hist[i];
        if (c) atomicAdd(&out[batch * NBINS + i], (float)c * invP);
    }
}

extern "C" void kernel_launch(void* const* d_in, const int* in_sizes, int n_in,
                              void* d_out, int out_size, void* d_ws, size_t ws_size,
                              hipStream_t stream) {
    const float* in = (const float*)d_in[0];
    float* out = (float*)d_out;
    // d_out is poisoned to 0xAA before every timed launch — zero it (memset node is graph-capturable).
    hipMemsetAsync(out, 0, (size_t)out_size * sizeof(float), stream);
    Probability_66048007078103_kernel<<<BATCHES * BLOCKS_PER_BATCH, 256, 0, stream>>>(in, out);
}